// Round 1
// baseline (8751.347 us; speedup 1.0000x reference)
//
#include <hip/hip_runtime.h>
#include <cmath>

// Problem constants (match reference)
constexpr int   BB  = 128;    // batch
constexpr int   LL  = 128;    // timesteps
constexpr int   NH  = 2048;   // hidden (cols)
constexpr int   KD  = 2048;   // reduction dim (= NH)
constexpr float DTc   = 0.042f;
constexpr float THETAc= 0.1f;
constexpr float ALPHAc= 0.3f;
constexpr float BETAc = 0.4f;
// ref_decay = exp(-DT/TAU_REF) = exp(-0.168)

// One recurrence step, fused: pre = tanh(x*x2h + hy@W + bias); cell update; spike accum.
// Grid: (32, 8) blocks; block tile = 64 cols x 16 rows; 512 threads; thread = 1 col x 2 rows.
__global__ __launch_bounds__(512) void step_kernel(
    const float* __restrict__ hy_in, float* __restrict__ hy_out,
    float* __restrict__ hz, float* __restrict__ refb, float* __restrict__ ssum,
    const float* __restrict__ W, const float* __restrict__ x2h,
    const float* __restrict__ bias, const float* __restrict__ gamma,
    const float* __restrict__ eps, const float* __restrict__ x, int t)
{
    const int tx = threadIdx.x & 63;                                   // col within block
    const int wy = __builtin_amdgcn_readfirstlane((int)(threadIdx.x >> 6)); // wave id 0..7 (uniform)
    const int n  = blockIdx.x * 64 + tx;
    const int b0 = blockIdx.y * 16 + wy * 2;

    const float* __restrict__ h0 = hy_in + (size_t)b0 * KD;
    const float* __restrict__ h1 = h0 + KD;

    float acc0 = 0.f, acc1 = 0.f;
    for (int k = 0; k < KD; k += 8) {
        // wave-uniform hy loads (scalar pipe), 8 k's for 2 rows
        float4 ha0 = *(const float4*)(h0 + k);
        float4 ha1 = *(const float4*)(h0 + k + 4);
        float4 hb0 = *(const float4*)(h1 + k);
        float4 hb1 = *(const float4*)(h1 + k + 4);
        float av[8] = { ha0.x, ha0.y, ha0.z, ha0.w, ha1.x, ha1.y, ha1.z, ha1.w };
        float bv[8] = { hb0.x, hb0.y, hb0.z, hb0.w, hb1.x, hb1.y, hb1.z, hb1.w };
        #pragma unroll
        for (int kk = 0; kk < 8; ++kk) {
            float w = W[(size_t)(k + kk) * NH + n];   // coalesced across lanes
            acc0 = fmaf(av[kk], w, acc0);
            acc1 = fmaf(bv[kk], w, acc1);
        }
    }

    const float xb = x2h[n];
    const float bi = bias[n];
    const float ga = gamma[n];
    const float ep = eps[n];
    const float rd = expf(-DTc / 0.25f);

    #pragma unroll
    for (int j = 0; j < 2; ++j) {
        const int b = b0 + j;
        float acc = j ? acc1 : acc0;
        const float xt = x[(size_t)b * LL + t];
        float pre = tanhf(acc + xt * xb + bi);
        const size_t idx = (size_t)b * NH + n;
        float hyv = hy_in[idx];
        float hzv = hz[idx];
        float rf  = refb[idx];
        hzv += DTc * (pre - ga * hyv - ep * hzv);
        hyv += DTc * hzv;
        float s = (hyv - THETAc - rf > 0.f) ? 1.f : 0.f;
        hyv *= 1.f - s * ALPHAc;
        hzv *= 1.f - s * BETAc;
        rf = rf * rd + s;
        hy_out[idx] = hyv;
        hz[idx]     = hzv;
        refb[idx]   = rf;
        ssum[idx]  += s;
    }
}

__global__ __launch_bounds__(512) void finish_kernel(const float* __restrict__ ssum,
                                                     float* __restrict__ out)
{
    const int i = blockIdx.x * 512 + threadIdx.x;
    out[i] = ssum[i] * (1.0f / (float)LL);
}

extern "C" void kernel_launch(void* const* d_in, const int* in_sizes, int n_in,
                              void* d_out, int out_size, void* d_ws, size_t ws_size,
                              hipStream_t stream) {
    const float* x     = (const float*)d_in[0];  // (B, L, 1)
    const float* W     = (const float*)d_in[1];  // (NH, NH) = h2h, row-major [k][n]
    const float* x2h   = (const float*)d_in[2];  // (1, NH)
    const float* bias  = (const float*)d_in[3];  // (NH)
    const float* gamma = (const float*)d_in[4];  // (NH)
    const float* eps   = (const float*)d_in[5];  // (NH)
    float* out = (float*)d_out;

    float* ws = (float*)d_ws;
    const size_t S = (size_t)BB * NH;       // 262144 elements = 1 MB
    float* hyA = ws;
    float* hyB = ws + S;
    float* hz  = ws + 2 * S;
    float* rf  = ws + 3 * S;
    float* ss  = ws + 4 * S;

    // zero state + spike accumulator (ws is poisoned; must re-init every call)
    hipMemsetAsync(d_ws, 0, 5 * S * sizeof(float), stream);

    dim3 grid(NH / 64, BB / 16);   // (32, 8) = 256 blocks
    dim3 blk(512);

    const float* hin = hyA;
    float* hout = hyB;
    for (int t = 0; t < LL; ++t) {
        step_kernel<<<grid, blk, 0, stream>>>(hin, hout, hz, rf, ss,
                                              W, x2h, bias, gamma, eps, x, t);
        const float* tmp = hout;
        hout = (float*)hin;
        hin  = tmp;
    }

    finish_kernel<<<S / 512, 512, 0, stream>>>(ss, out);
}

// Round 2
// 6772.016 us; speedup vs baseline: 1.2923x; 1.2923x over previous
//
#include <hip/hip_runtime.h>
#include <cmath>

// Problem constants (match reference)
constexpr int   BB  = 128;    // batch
constexpr int   LL  = 128;    // timesteps
constexpr int   NH  = 2048;   // hidden (cols)
constexpr int   KD  = 2048;   // reduction dim (= NH)
constexpr int   KQ  = 4;      // split-K factor
constexpr int   KCH = KD / KQ;       // 512 k per block
constexpr float DTc   = 0.042f;
constexpr float THETAc= 0.1f;
constexpr float ALPHAc= 0.3f;
constexpr float BETAc = 0.4f;

// GEMM partial: P[kq][b][n] = sum_{k in chunk kq} hy[b][k] * W[k][n]
// Grid (32, 2, 4) = 256 blocks, 512 threads.
// Block tile: 64 cols x 64 rows; wave w owns rows rowbase + w*8 .. +8 (uniform),
// lane owns one col. 8 accumulator chains/thread -> FMA:VMEM = 8:1.
__global__ __launch_bounds__(512) void gemm_kernel(
    const float* __restrict__ hy_in, float* __restrict__ P,
    const float* __restrict__ W)
{
    const int lane = threadIdx.x & 63;
    const int w    = __builtin_amdgcn_readfirstlane((int)(threadIdx.x >> 6)); // 0..7
    const int n        = blockIdx.x * 64 + lane;
    const int rowbase  = blockIdx.y * 64 + w * 8;
    const int kq       = blockIdx.z;
    const int k0       = kq * KCH;

    const float* __restrict__ hp = hy_in + (size_t)rowbase * KD + k0; // wave-uniform
    const float* __restrict__ Wp = W + (size_t)k0 * NH + n;

    float acc[8] = {0.f,0.f,0.f,0.f,0.f,0.f,0.f,0.f};
    float wc[8], wn[8];

    #pragma unroll
    for (int i = 0; i < 8; ++i) wn[i] = Wp[(size_t)i * NH];

    for (int k = 0; k < KCH; k += 8) {
        #pragma unroll
        for (int i = 0; i < 8; ++i) wc[i] = wn[i];
        if (k + 8 < KCH) {
            const float* Wq = Wp + (size_t)(k + 8) * NH;
            #pragma unroll
            for (int i = 0; i < 8; ++i) wn[i] = Wq[(size_t)i * NH];
        }
        #pragma unroll
        for (int j = 0; j < 8; ++j) {
            const float* hr = hp + (size_t)j * KD + k;   // wave-uniform -> scalar loads
            float4 a = *(const float4*)(hr);
            float4 b = *(const float4*)(hr + 4);
            acc[j] = fmaf(a.x, wc[0], acc[j]);
            acc[j] = fmaf(a.y, wc[1], acc[j]);
            acc[j] = fmaf(a.z, wc[2], acc[j]);
            acc[j] = fmaf(a.w, wc[3], acc[j]);
            acc[j] = fmaf(b.x, wc[4], acc[j]);
            acc[j] = fmaf(b.y, wc[5], acc[j]);
            acc[j] = fmaf(b.z, wc[6], acc[j]);
            acc[j] = fmaf(b.w, wc[7], acc[j]);
        }
    }

    float* Pp = P + ((size_t)kq * BB + rowbase) * NH + n;
    #pragma unroll
    for (int j = 0; j < 8; ++j) Pp[(size_t)j * NH] = acc[j];
}

// Per-step epilogue: sum 4 partials (fixed order), cell update, spike accum.
__global__ __launch_bounds__(256) void update_kernel(
    const float* __restrict__ P, const float* __restrict__ hy_in,
    float* __restrict__ hy_out, float* __restrict__ hz,
    float* __restrict__ refb, float* __restrict__ ssum,
    const float* __restrict__ x2h, const float* __restrict__ bias,
    const float* __restrict__ gamma, const float* __restrict__ eps,
    const float* __restrict__ x, int t)
{
    const int i = blockIdx.x * 256 + threadIdx.x;   // over B*NH
    const int b = i >> 11;
    const int n = i & (NH - 1);
    const size_t S = (size_t)BB * NH;

    float acc = (P[i] + P[S + i]) + (P[2 * S + i] + P[3 * S + i]);

    const float xt = x[(size_t)b * LL + t];
    float pre = tanhf(acc + xt * x2h[n] + bias[n]);

    float hyv = hy_in[i];
    float hzv = hz[i];
    float rf  = refb[i];
    const float rd = expf(-DTc / 0.25f);

    hzv += DTc * (pre - gamma[n] * hyv - eps[n] * hzv);
    hyv += DTc * hzv;
    float s = (hyv - THETAc - rf > 0.f) ? 1.f : 0.f;
    hyv *= 1.f - s * ALPHAc;
    hzv *= 1.f - s * BETAc;
    rf = rf * rd + s;

    hy_out[i] = hyv;
    hz[i]     = hzv;
    refb[i]   = rf;
    ssum[i]  += s;
}

__global__ __launch_bounds__(512) void finish_kernel(const float* __restrict__ ssum,
                                                     float* __restrict__ out)
{
    const int i = blockIdx.x * 512 + threadIdx.x;
    out[i] = ssum[i] * (1.0f / (float)LL);
}

extern "C" void kernel_launch(void* const* d_in, const int* in_sizes, int n_in,
                              void* d_out, int out_size, void* d_ws, size_t ws_size,
                              hipStream_t stream) {
    const float* x     = (const float*)d_in[0];  // (B, L, 1)
    const float* W     = (const float*)d_in[1];  // (NH, NH) row-major [k][n]
    const float* x2h   = (const float*)d_in[2];  // (1, NH)
    const float* bias  = (const float*)d_in[3];  // (NH)
    const float* gamma = (const float*)d_in[4];  // (NH)
    const float* eps   = (const float*)d_in[5];  // (NH)
    float* out = (float*)d_out;

    float* ws = (float*)d_ws;
    const size_t S = (size_t)BB * NH;   // 262144
    // layout: [hyA][hz][rf][ss][hyB][P(4S)] = 9S floats = 9 MB
    float* hyA = ws;
    float* hz  = ws + S;
    float* rf  = ws + 2 * S;
    float* ss  = ws + 3 * S;
    float* hyB = ws + 4 * S;
    float* P   = ws + 5 * S;

    // zero state + spike accumulator (hyB fully written by epilogue t=0,
    // P fully written by gemm t=0 — no init needed for those)
    hipMemsetAsync(d_ws, 0, 4 * S * sizeof(float), stream);

    dim3 ggrid(NH / 64, BB / 64, KQ);   // (32, 2, 4) = 256 blocks
    dim3 gblk(512);
    dim3 ugrid(S / 256);
    dim3 ublk(256);

    const float* hin = hyA;
    float* hout = hyB;
    for (int t = 0; t < LL; ++t) {
        gemm_kernel<<<ggrid, gblk, 0, stream>>>(hin, P, W);
        update_kernel<<<ugrid, ublk, 0, stream>>>(P, hin, hout, hz, rf, ss,
                                                  x2h, bias, gamma, eps, x, t);
        const float* tmp = hout;
        hout = (float*)hin;
        hin  = tmp;
    }

    finish_kernel<<<S / 512, 512, 0, stream>>>(ss, out);
}

// Round 3
// 5149.003 us; speedup vs baseline: 1.6996x; 1.3152x over previous
//
#include <hip/hip_runtime.h>
#include <cmath>

// Problem constants (match reference)
constexpr int   BB  = 128;    // batch
constexpr int   LL  = 128;    // timesteps
constexpr int   NH  = 2048;   // hidden (cols)
constexpr int   KD  = 2048;   // reduction dim (= NH)
constexpr float DTc   = 0.042f;
constexpr float THETAc= 0.1f;
constexpr float ALPHAc= 0.3f;
constexpr float BETAc = 0.4f;

// GEMM partial: P[kq][b][n] = sum_{k in chunk kq} hy[b][k] * W[k][n]
// Block tile: 64 cols x 64 rows; wave w owns 8 rows (uniform), lane owns one col.
// 8 accumulator chains/thread (FMA:VMEM = 8:1); depth-2 W prefetch.
template<int KCH>
__global__ __launch_bounds__(512) void gemm_kernel(
    const float* __restrict__ hy_in, float* __restrict__ P,
    const float* __restrict__ W)
{
    const int lane = threadIdx.x & 63;
    const int w    = __builtin_amdgcn_readfirstlane((int)(threadIdx.x >> 6)); // 0..7
    const int n        = blockIdx.x * 64 + lane;
    const int rowbase  = blockIdx.y * 64 + w * 8;
    const int kq       = blockIdx.z;
    const int k0       = kq * KCH;

    const float* __restrict__ hp = hy_in + (size_t)rowbase * KD + k0; // wave-uniform
    const float* __restrict__ Wp = W + (size_t)k0 * NH + n;

    float acc[8] = {0.f,0.f,0.f,0.f,0.f,0.f,0.f,0.f};
    float wc[8], w1[8], w2[8];

    // prefetch iterations 0 and 1
    #pragma unroll
    for (int i = 0; i < 8; ++i) w1[i] = Wp[(size_t)i * NH];
    {
        const float* Wq = Wp + (size_t)8 * NH;
        #pragma unroll
        for (int i = 0; i < 8; ++i) w2[i] = Wq[(size_t)i * NH];
    }

    for (int k = 0; k < KCH; k += 8) {
        #pragma unroll
        for (int i = 0; i < 8; ++i) wc[i] = w1[i];
        #pragma unroll
        for (int i = 0; i < 8; ++i) w1[i] = w2[i];
        if (k + 16 < KCH) {
            const float* Wq = Wp + (size_t)(k + 16) * NH;
            #pragma unroll
            for (int i = 0; i < 8; ++i) w2[i] = Wq[(size_t)i * NH];
        }
        #pragma unroll
        for (int j = 0; j < 8; ++j) {
            const float* hr = hp + (size_t)j * KD + k;   // wave-uniform -> scalar loads
            float4 a = *(const float4*)(hr);
            float4 b = *(const float4*)(hr + 4);
            acc[j] = fmaf(a.x, wc[0], acc[j]);
            acc[j] = fmaf(a.y, wc[1], acc[j]);
            acc[j] = fmaf(a.z, wc[2], acc[j]);
            acc[j] = fmaf(a.w, wc[3], acc[j]);
            acc[j] = fmaf(b.x, wc[4], acc[j]);
            acc[j] = fmaf(b.y, wc[5], acc[j]);
            acc[j] = fmaf(b.z, wc[6], acc[j]);
            acc[j] = fmaf(b.w, wc[7], acc[j]);
        }
    }

    float* Pp = P + ((size_t)kq * BB + rowbase) * NH + n;
    #pragma unroll
    for (int j = 0; j < 8; ++j) Pp[(size_t)j * NH] = acc[j];
}

// Per-step epilogue: sum partials (fixed order), cell update, spike accum.
__global__ __launch_bounds__(256) void update_kernel(
    const float* __restrict__ P, int kqn, const float* __restrict__ hy_in,
    float* __restrict__ hy_out, float* __restrict__ hz,
    float* __restrict__ refb, float* __restrict__ ssum,
    const float* __restrict__ x2h, const float* __restrict__ bias,
    const float* __restrict__ gamma, const float* __restrict__ eps,
    const float* __restrict__ x, int t)
{
    const int i = blockIdx.x * 256 + threadIdx.x;   // over B*NH
    const int b = i >> 11;
    const int n = i & (NH - 1);
    const size_t S = (size_t)BB * NH;

    float acc = 0.f;
    for (int q = 0; q < kqn; ++q) acc += P[(size_t)q * S + i];  // fixed order

    const float xt = x[(size_t)b * LL + t];
    float pre = tanhf(acc + xt * x2h[n] + bias[n]);

    float hyv = hy_in[i];
    float hzv = hz[i];
    float rf  = refb[i];
    const float rd = expf(-DTc / 0.25f);

    hzv += DTc * (pre - gamma[n] * hyv - eps[n] * hzv);
    hyv += DTc * hzv;
    float s = (hyv - THETAc - rf > 0.f) ? 1.f : 0.f;
    hyv *= 1.f - s * ALPHAc;
    hzv *= 1.f - s * BETAc;
    rf = rf * rd + s;

    hy_out[i] = hyv;
    hz[i]     = hzv;
    refb[i]   = rf;
    ssum[i]  += s;
}

__global__ __launch_bounds__(512) void finish_kernel(const float* __restrict__ ssum,
                                                     float* __restrict__ out)
{
    const int i = blockIdx.x * 512 + threadIdx.x;
    out[i] = ssum[i] * (1.0f / (float)LL);
}

extern "C" void kernel_launch(void* const* d_in, const int* in_sizes, int n_in,
                              void* d_out, int out_size, void* d_ws, size_t ws_size,
                              hipStream_t stream) {
    const float* x     = (const float*)d_in[0];  // (B, L, 1)
    const float* W     = (const float*)d_in[1];  // (NH, NH) row-major [k][n]
    const float* x2h   = (const float*)d_in[2];  // (1, NH)
    const float* bias  = (const float*)d_in[3];  // (NH)
    const float* gamma = (const float*)d_in[4];  // (NH)
    const float* eps   = (const float*)d_in[5];  // (NH)
    float* out = (float*)d_out;

    float* ws = (float*)d_ws;
    const size_t S = (size_t)BB * NH;   // 262144
    // layout: [hyA][hz][rf][ss][hyB][P(KQ*S)]
    float* hyA = ws;
    float* hz  = ws + S;
    float* rf  = ws + 2 * S;
    float* ss  = ws + 3 * S;
    float* hyB = ws + 4 * S;
    float* P   = ws + 5 * S;

    // KQ=8 needs 13*S floats; fall back to 4 if workspace is short.
    const int KQ = (ws_size >= 13 * S * sizeof(float)) ? 8 : 4;

    hipMemsetAsync(d_ws, 0, 4 * S * sizeof(float), stream);

    dim3 ggrid(NH / 64, BB / 64, KQ);   // (32, 2, KQ)
    dim3 gblk(512);
    dim3 ugrid((unsigned)(S / 256));
    dim3 ublk(256);

    const float* hin = hyA;
    float* hout = hyB;
    for (int t = 0; t < LL; ++t) {
        if (KQ == 8)
            gemm_kernel<KD / 8><<<ggrid, gblk, 0, stream>>>(hin, P, W);
        else
            gemm_kernel<KD / 4><<<ggrid, gblk, 0, stream>>>(hin, P, W);
        update_kernel<<<ugrid, ublk, 0, stream>>>(P, KQ, hin, hout, hz, rf, ss,
                                                  x2h, bias, gamma, eps, x, t);
        const float* tmp = hout;
        hout = (float*)hin;
        hin  = tmp;
    }

    finish_kernel<<<S / 512, 512, 0, stream>>>(ss, out);
}

// Round 4
// 2149.671 us; speedup vs baseline: 4.0710x; 2.3953x over previous
//
#include <hip/hip_runtime.h>
#include <hip/hip_bf16.h>
#include <cmath>

// Problem constants
constexpr int   BB  = 128;    // batch (GEMM M)
constexpr int   LL  = 128;    // timesteps
constexpr int   NH  = 2048;   // hidden (GEMM N)
constexpr int   KD  = 2048;   // reduction dim
constexpr int   KQ  = 8;      // split-K for MFMA path
constexpr float DTc   = 0.042f;
constexpr float THETAc= 0.1f;
constexpr float ALPHAc= 0.3f;
constexpr float BETAc = 0.4f;

typedef float f32x4 __attribute__((ext_vector_type(4)));
typedef short s16x8 __attribute__((ext_vector_type(8)));

__device__ inline ushort f2bf(float f) {
    union { __hip_bfloat16 h; ushort u; } v; v.h = __float2bfloat16(f); return v.u;
}
__device__ inline float bf2f(ushort u) {
    union { ushort u; __hip_bfloat16 h; } v; v.u = u; return __bfloat162float(v.h);
}
// Exact 3-way bf16 split: f == b1 + b2 + b3 (for normal-range values)
__device__ inline void split3(float f, ushort& b1, ushort& b2, ushort& b3) {
    b1 = f2bf(f);  float r  = f - bf2f(b1);
    b2 = f2bf(r);  float r2 = r - bf2f(b2);
    b3 = f2bf(r2);
}

// ---------------- MFMA path ----------------
// Fragment layouts (16x16x32 bf16 MFMA):
//   A: lane l holds A[m = base+(l&15)][k = kt*32 + (l>>4)*8 + e], e=0..7
//   B: lane l holds B[k = kt*32 + (l>>4)*8 + e][n = base+(l&15)]
//   C: reg r: row=(l>>4)*4+r, col=(l&15)   [m89-verified]
// Pre-swizzled global storage so every fragment load is a coalesced dwordx4:
//   Af[s]: idx = ((kt*4+g)*128 + m)*8 + e          (S shorts per split)
//   Bf[s]: idx = (((kt*128) + nb)*64 + lane)*8 + e (4M shorts per split)

__global__ __launch_bounds__(256) void packB_kernel(
    const float* __restrict__ W, ushort* __restrict__ B1,
    ushort* __restrict__ B2, ushort* __restrict__ B3)
{
    const int gw   = blockIdx.x * 4 + (threadIdx.x >> 6);   // 0..8191
    const int lane = threadIdx.x & 63;
    const int kt = gw >> 7;          // 0..63
    const int nb = gw & 127;         // 0..127
    const size_t ob = ((size_t)(kt * 128 + nb) * 64 + lane) * 8;
    const int k0 = kt * 32 + (lane >> 4) * 8;
    const int n  = nb * 16 + (lane & 15);
    #pragma unroll
    for (int e = 0; e < 8; ++e) {
        float w = W[(size_t)(k0 + e) * NH + n];
        ushort x1, x2, x3; split3(w, x1, x2, x3);
        B1[ob + e] = x1; B2[ob + e] = x2; B3[ob + e] = x3;
    }
}

// Grid (32, 8): bx = 64-col tile, by = kq. 512 thr = 8 waves; wave tile 32x32.
__global__ __launch_bounds__(512) void gemm_mfma(
    const ushort* __restrict__ A1, const ushort* __restrict__ A2,
    const ushort* __restrict__ A3, const ushort* __restrict__ B1,
    const ushort* __restrict__ B2, const ushort* __restrict__ B3,
    float* __restrict__ P)
{
    const int lane = threadIdx.x & 63;
    const int w    = threadIdx.x >> 6;      // 0..7
    const int wm   = w >> 1;                // 0..3 (M 32-row strip)
    const int wn   = w & 1;                 // 0..1 (N 32-col strip)
    const int g    = lane >> 4;
    const int r16  = lane & 15;
    const int bx   = blockIdx.x;            // 0..31
    const int kq   = blockIdx.y;            // 0..7
    const int nb0  = bx * 4 + wn * 2;

    f32x4 acc[2][2] = {};

    for (int i = 0; i < 8; ++i) {
        const int kt = kq * 8 + i;
        const size_t ab = ((size_t)(kt * 4 + g) * 128 + wm * 32 + r16) * 8;
        const size_t bb = ((size_t)(kt * 128 + nb0) * 64 + lane) * 8;

        s16x8 a1[2], a2[2], a3[2], b1[2], b2[2], b3[2];
        #pragma unroll
        for (int mf = 0; mf < 2; ++mf) {
            a1[mf] = *(const s16x8*)(A1 + ab + mf * 128);
            a2[mf] = *(const s16x8*)(A2 + ab + mf * 128);
            a3[mf] = *(const s16x8*)(A3 + ab + mf * 128);
        }
        #pragma unroll
        for (int nf = 0; nf < 2; ++nf) {
            b1[nf] = *(const s16x8*)(B1 + bb + nf * 512);
            b2[nf] = *(const s16x8*)(B2 + bb + nf * 512);
            b3[nf] = *(const s16x8*)(B3 + bb + nf * 512);
        }
        #pragma unroll
        for (int mf = 0; mf < 2; ++mf)
        #pragma unroll
        for (int nf = 0; nf < 2; ++nf) {
            f32x4 c = acc[mf][nf];
            c = __builtin_amdgcn_mfma_f32_16x16x32_bf16(a1[mf], b1[nf], c, 0, 0, 0);
            c = __builtin_amdgcn_mfma_f32_16x16x32_bf16(a1[mf], b2[nf], c, 0, 0, 0);
            c = __builtin_amdgcn_mfma_f32_16x16x32_bf16(a2[mf], b1[nf], c, 0, 0, 0);
            c = __builtin_amdgcn_mfma_f32_16x16x32_bf16(a1[mf], b3[nf], c, 0, 0, 0);
            c = __builtin_amdgcn_mfma_f32_16x16x32_bf16(a2[mf], b2[nf], c, 0, 0, 0);
            c = __builtin_amdgcn_mfma_f32_16x16x32_bf16(a3[mf], b1[nf], c, 0, 0, 0);
            acc[mf][nf] = c;
        }
    }

    const size_t S = (size_t)BB * NH;
    float* Pp = P + (size_t)kq * S;
    #pragma unroll
    for (int mf = 0; mf < 2; ++mf)
    #pragma unroll
    for (int nf = 0; nf < 2; ++nf) {
        const int col = bx * 64 + wn * 32 + nf * 16 + r16;
        #pragma unroll
        for (int r = 0; r < 4; ++r) {
            const int row = wm * 32 + mf * 16 + g * 4 + r;
            Pp[(size_t)row * NH + col] = acc[mf][nf][r];
        }
    }
}

// Epilogue: sum KQ partials, cell update, spike accum, write next A-splits.
__global__ __launch_bounds__(256) void update_mfma(
    const float* __restrict__ P, float* __restrict__ hy,
    float* __restrict__ hz, float* __restrict__ refb, float* __restrict__ ssum,
    ushort* __restrict__ A1, ushort* __restrict__ A2, ushort* __restrict__ A3,
    const float* __restrict__ x2h, const float* __restrict__ bias,
    const float* __restrict__ gamma, const float* __restrict__ eps,
    const float* __restrict__ x, int t)
{
    const int i = blockIdx.x * 256 + threadIdx.x;
    const int b = i >> 11;
    const int n = i & (NH - 1);
    const size_t S = (size_t)BB * NH;

    float acc = 0.f;
    #pragma unroll
    for (int q = 0; q < KQ; ++q) acc += P[(size_t)q * S + i];

    const float xt = x[(size_t)b * LL + t];
    float pre = tanhf(acc + xt * x2h[n] + bias[n]);

    float hyv = hy[i];
    float hzv = hz[i];
    float rf  = refb[i];
    const float rd = expf(-DTc / 0.25f);

    hzv += DTc * (pre - gamma[n] * hyv - eps[n] * hzv);
    hyv += DTc * hzv;
    float s = (hyv - THETAc - rf > 0.f) ? 1.f : 0.f;
    hyv *= 1.f - s * ALPHAc;
    hzv *= 1.f - s * BETAc;
    rf = rf * rd + s;

    hy[i]   = hyv;
    hz[i]   = hzv;
    refb[i] = rf;
    ssum[i] += s;

    // write A-fragment splits of hy for next step's gemm
    const int kt = n >> 5, g = (n >> 3) & 3, e = n & 7;
    const size_t o = ((size_t)(kt * 4 + g) * 128 + b) * 8 + e;
    ushort x1, x2, x3; split3(hyv, x1, x2, x3);
    A1[o] = x1; A2[o] = x2; A3[o] = x3;
}

__global__ __launch_bounds__(512) void finish_kernel(const float* __restrict__ ssum,
                                                     float* __restrict__ out)
{
    const int i = blockIdx.x * 512 + threadIdx.x;
    out[i] = ssum[i] * (1.0f / (float)LL);
}

// ---------------- fallback vector path (round-3) ----------------
template<int KCH>
__global__ __launch_bounds__(512) void gemm_vec(
    const float* __restrict__ hy_in, float* __restrict__ P,
    const float* __restrict__ W)
{
    const int lane = threadIdx.x & 63;
    const int w    = __builtin_amdgcn_readfirstlane((int)(threadIdx.x >> 6));
    const int n        = blockIdx.x * 64 + lane;
    const int rowbase  = blockIdx.y * 64 + w * 8;
    const int kq       = blockIdx.z;
    const int k0       = kq * KCH;

    const float* __restrict__ hp = hy_in + (size_t)rowbase * KD + k0;
    const float* __restrict__ Wp = W + (size_t)k0 * NH + n;

    float acc[8] = {0.f,0.f,0.f,0.f,0.f,0.f,0.f,0.f};
    float wc[8], w1[8], w2[8];
    #pragma unroll
    for (int i = 0; i < 8; ++i) w1[i] = Wp[(size_t)i * NH];
    {
        const float* Wq = Wp + (size_t)8 * NH;
        #pragma unroll
        for (int i = 0; i < 8; ++i) w2[i] = Wq[(size_t)i * NH];
    }
    for (int k = 0; k < KCH; k += 8) {
        #pragma unroll
        for (int i = 0; i < 8; ++i) wc[i] = w1[i];
        #pragma unroll
        for (int i = 0; i < 8; ++i) w1[i] = w2[i];
        if (k + 16 < KCH) {
            const float* Wq = Wp + (size_t)(k + 16) * NH;
            #pragma unroll
            for (int i = 0; i < 8; ++i) w2[i] = Wq[(size_t)i * NH];
        }
        #pragma unroll
        for (int j = 0; j < 8; ++j) {
            const float* hr = hp + (size_t)j * KD + k;
            float4 a = *(const float4*)(hr);
            float4 b = *(const float4*)(hr + 4);
            acc[j] = fmaf(a.x, wc[0], acc[j]); acc[j] = fmaf(a.y, wc[1], acc[j]);
            acc[j] = fmaf(a.z, wc[2], acc[j]); acc[j] = fmaf(a.w, wc[3], acc[j]);
            acc[j] = fmaf(b.x, wc[4], acc[j]); acc[j] = fmaf(b.y, wc[5], acc[j]);
            acc[j] = fmaf(b.z, wc[6], acc[j]); acc[j] = fmaf(b.w, wc[7], acc[j]);
        }
    }
    float* Pp = P + ((size_t)kq * BB + rowbase) * NH + n;
    #pragma unroll
    for (int j = 0; j < 8; ++j) Pp[(size_t)j * NH] = acc[j];
}

__global__ __launch_bounds__(256) void update_vec(
    const float* __restrict__ P, int kqn, const float* __restrict__ hy_in,
    float* __restrict__ hy_out, float* __restrict__ hz,
    float* __restrict__ refb, float* __restrict__ ssum,
    const float* __restrict__ x2h, const float* __restrict__ bias,
    const float* __restrict__ gamma, const float* __restrict__ eps,
    const float* __restrict__ x, int t)
{
    const int i = blockIdx.x * 256 + threadIdx.x;
    const int b = i >> 11;
    const int n = i & (NH - 1);
    const size_t S = (size_t)BB * NH;
    float acc = 0.f;
    for (int q = 0; q < kqn; ++q) acc += P[(size_t)q * S + i];
    const float xt = x[(size_t)b * LL + t];
    float pre = tanhf(acc + xt * x2h[n] + bias[n]);
    float hyv = hy_in[i];
    float hzv = hz[i];
    float rf  = refb[i];
    const float rd = expf(-DTc / 0.25f);
    hzv += DTc * (pre - gamma[n] * hyv - eps[n] * hzv);
    hyv += DTc * hzv;
    float s = (hyv - THETAc - rf > 0.f) ? 1.f : 0.f;
    hyv *= 1.f - s * ALPHAc;
    hzv *= 1.f - s * BETAc;
    rf = rf * rd + s;
    hy_out[i] = hyv; hz[i] = hzv; refb[i] = rf; ssum[i] += s;
}

extern "C" void kernel_launch(void* const* d_in, const int* in_sizes, int n_in,
                              void* d_out, int out_size, void* d_ws, size_t ws_size,
                              hipStream_t stream) {
    const float* x     = (const float*)d_in[0];
    const float* W     = (const float*)d_in[1];
    const float* x2h   = (const float*)d_in[2];
    const float* bias  = (const float*)d_in[3];
    const float* gamma = (const float*)d_in[4];
    const float* eps   = (const float*)d_in[5];
    float* out = (float*)d_out;

    const size_t S  = (size_t)BB * NH;          // 262144
    const size_t SB = S * sizeof(float);        // 1 MB

    // MFMA-path workspace: states 4MB | Af 1.5MB | P 8MB | Bf 24MB = 37.5MB
    const size_t need_mfma = 4 * SB + 3 * (S * 2) + (size_t)KQ * SB + 3 * (4 * S * 2 * 4);
    // = 4MB + 1.5MB + 8MB + 24MB

    if (ws_size >= need_mfma) {
        char* base = (char*)d_ws;
        float*  hy = (float*)(base);
        float*  hz = (float*)(base + SB);
        float*  rf = (float*)(base + 2 * SB);
        float*  ss = (float*)(base + 3 * SB);
        ushort* A1 = (ushort*)(base + 4 * SB);
        ushort* A2 = A1 + S;
        ushort* A3 = A2 + S;
        float*  P  = (float*)(base + 4 * SB + 3 * S * 2);           // +5.5MB
        ushort* B1 = (ushort*)((char*)P + (size_t)KQ * SB);         // +13.5MB
        ushort* B2 = B1 + 4 * S * 4;                                // 8MB each
        ushort* B3 = B2 + 4 * S * 4;

        // zero states + A-splits (5.5MB); hy(0)=0 -> A-frags zero ✓
        hipMemsetAsync(d_ws, 0, 4 * SB + 3 * S * 2, stream);

        packB_kernel<<<2048, 256, 0, stream>>>(W, B1, B2, B3);

        dim3 ggrid(NH / 64, KQ);    // (32, 8)
        for (int t = 0; t < LL; ++t) {
            gemm_mfma<<<ggrid, 512, 0, stream>>>(A1, A2, A3, B1, B2, B3, P);
            update_mfma<<<(unsigned)(S / 256), 256, 0, stream>>>(
                P, hy, hz, rf, ss, A1, A2, A3, x2h, bias, gamma, eps, x, t);
        }
        finish_kernel<<<(unsigned)(S / 512), 512, 0, stream>>>(ss, out);
    } else {
        // vector fallback (round-3)
        float* ws = (float*)d_ws;
        float* hyA = ws;
        float* hz  = ws + S;
        float* rf  = ws + 2 * S;
        float* ss  = ws + 3 * S;
        float* hyB = ws + 4 * S;
        float* P   = ws + 5 * S;
        const int kq = (ws_size >= 13 * SB) ? 8 : 4;
        hipMemsetAsync(d_ws, 0, 4 * SB, stream);
        dim3 ggrid(NH / 64, BB / 64, kq);
        const float* hin = hyA;
        float* hout = hyB;
        for (int t = 0; t < LL; ++t) {
            if (kq == 8)
                gemm_vec<KD / 8><<<ggrid, 512, 0, stream>>>(hin, P, W);
            else
                gemm_vec<KD / 4><<<ggrid, 512, 0, stream>>>(hin, P, W);
            update_vec<<<(unsigned)(S / 256), 256, 0, stream>>>(
                P, kq, hin, hout, hz, rf, ss, x2h, bias, gamma, eps, x, t);
            const float* tmp = hout; hout = (float*)hin; hin = tmp;
        }
        finish_kernel<<<(unsigned)(S / 512), 512, 0, stream>>>(ss, out);
    }
}